// Round 1
// baseline (424.441 us; speedup 1.0000x reference)
//
#include <hip/hip_runtime.h>

typedef __attribute__((ext_vector_type(8))) short bf16x8;
typedef __attribute__((ext_vector_type(4))) float f32x4;

__device__ __forceinline__ unsigned short f2bf(float f) {
  union { float f; unsigned u; } a; a.f = f;
  unsigned u = a.u;
  unsigned r = (u + 0x7FFFu + ((u >> 16) & 1u)) >> 16;  // round-nearest-even
  return (unsigned short)r;
}

__device__ __forceinline__ void stage16(const void* g, void* l) {
  __builtin_amdgcn_global_load_lds((const __attribute__((address_space(1))) unsigned int*)g,
                                   (__attribute__((address_space(3))) unsigned int*)l,
                                   16, 0, 0);
}

// ---------------------------------------------------------------------------
// NT GEMM: C[m,n] = scale * sum_k A[m,k]*B[n,k] (+ bias)
// A: bf16 [M,K] row-major (lda), B: bf16 [N,K] row-major (ldb)
// OUT_BF16: write bf16 else fp32.  BIAS_MODE: 0 none, 1 bias[col], 2 bias[row]
// Tile 128x128, BK=32, 4 waves, 16x16x32 MFMA, global_load_lds staging.
// All dims must be multiples of 128 (M,N) and 32 (K) — true for this problem.
// ---------------------------------------------------------------------------
template<bool OUT_BF16, int BIAS_MODE>
__global__ __launch_bounds__(256) void gemm_nt(
    const unsigned short* __restrict__ A,
    const unsigned short* __restrict__ B,
    void* __restrict__ Cv,
    const float* __restrict__ bias,
    float scale, int K,
    int lda, int ldb, int ldc,
    long batchA, long batchB, long batchC)
{
  __shared__ __attribute__((aligned(16))) unsigned short lsA[128 * 32];
  __shared__ __attribute__((aligned(16))) unsigned short lsB[128 * 32];

  const int tid  = threadIdx.x;
  const int lane = tid & 63;
  const int wid  = tid >> 6;
  const long bz  = blockIdx.z;
  A += bz * batchA;
  B += bz * batchB;
  const int tileM = blockIdx.x * 128;
  const int tileN = blockIdx.y * 128;

  // staging: each thread loads 16B (8 bf16); 256 threads cover 64 rows x 32 cols
  const int sr = tid >> 2;          // 0..63
  const int sc = (tid & 3) << 3;    // 0,8,16,24
  const unsigned short* gA0 = A + (size_t)(tileM + sr) * lda + sc;
  const unsigned short* gA1 = A + (size_t)(tileM + 64 + sr) * lda + sc;
  const unsigned short* gB0 = B + (size_t)(tileN + sr) * ldb + sc;
  const unsigned short* gB1 = B + (size_t)(tileN + 64 + sr) * ldb + sc;
  unsigned short* dA0 = &lsA[tid * 8];
  unsigned short* dA1 = &lsA[2048 + tid * 8];
  unsigned short* dB0 = &lsB[tid * 8];
  unsigned short* dB1 = &lsB[2048 + tid * 8];

  f32x4 acc[4][4];
#pragma unroll
  for (int m = 0; m < 4; ++m)
#pragma unroll
    for (int n = 0; n < 4; ++n) acc[m][n] = (f32x4){0.f, 0.f, 0.f, 0.f};

  const int wr = (wid >> 1) << 6;   // wave row offset: 0 or 64
  const int wc = (wid & 1) << 6;    // wave col offset: 0 or 64
  const unsigned short* pa = &lsA[(wr + (lane & 15)) * 32 + ((lane >> 4) << 3)];
  const unsigned short* pb = &lsB[(wc + (lane & 15)) * 32 + ((lane >> 4) << 3)];

  for (int k0 = 0; k0 < K; k0 += 32) {
    stage16(gA0 + k0, dA0);
    stage16(gA1 + k0, dA1);
    stage16(gB0 + k0, dB0);
    stage16(gB1 + k0, dB1);
    __syncthreads();   // drains vmcnt before LDS reads

    bf16x8 af[4], bfr[4];
#pragma unroll
    for (int m = 0; m < 4; ++m) af[m]  = *(const bf16x8*)(pa + m * 16 * 32);
#pragma unroll
    for (int n = 0; n < 4; ++n) bfr[n] = *(const bf16x8*)(pb + n * 16 * 32);
#pragma unroll
    for (int m = 0; m < 4; ++m)
#pragma unroll
      for (int n = 0; n < 4; ++n)
        acc[m][n] = __builtin_amdgcn_mfma_f32_16x16x32_bf16(af[m], bfr[n], acc[m][n], 0, 0, 0);
    __syncthreads();   // protect LDS for next stage
  }

  // epilogue. C/D layout: col = lane&15, row = (lane>>4)*4 + reg  [m89-verified]
  const int ro = (lane >> 4) << 2;
  const int co = lane & 15;
#pragma unroll
  for (int m = 0; m < 4; ++m) {
#pragma unroll
    for (int n = 0; n < 4; ++n) {
      const int row0 = tileM + wr + m * 16 + ro;
      const int col  = tileN + wc + n * 16 + co;
#pragma unroll
      for (int r = 0; r < 4; ++r) {
        float v = acc[m][n][r] * scale;
        const int row = row0 + r;
        if (BIAS_MODE == 1) v += bias[col];
        if (BIAS_MODE == 2) v += bias[row];
        const size_t ci = (size_t)(bz * batchC) + (size_t)row * ldc + col;
        if (OUT_BF16) ((unsigned short*)Cv)[ci] = f2bf(v);
        else          ((float*)Cv)[ci] = v;
      }
    }
  }
}

// ---------------------------------------------------------------------------
// Row softmax over 2048 fp32 scores + intensity add, bf16 written IN-PLACE
// over the first half of each fp32 row (attn row i at bf16-elem offset i*4096).
// One block (256 thr) per row; all reads complete before any in-place write.
// ---------------------------------------------------------------------------
__global__ __launch_bounds__(256) void softmax_add_bf16(
    float* __restrict__ scores, const float* __restrict__ inten)
{
  const int row = blockIdx.x;                       // 0..8191
  float* srow = scores + (size_t)row * 2048;
  const float* irow = inten + (size_t)row * 2048;
  const int t = threadIdx.x;
  const int lane = t & 63, wid = t >> 6;

  float v[8];
  float mx = -3.4e38f;
#pragma unroll
  for (int j = 0; j < 8; ++j) { v[j] = srow[t + j * 256]; mx = fmaxf(mx, v[j]); }

  __shared__ float red[8];
#pragma unroll
  for (int o = 32; o; o >>= 1) mx = fmaxf(mx, __shfl_xor(mx, o));
  if (lane == 0) red[wid] = mx;
  __syncthreads();
  mx = fmaxf(fmaxf(red[0], red[1]), fmaxf(red[2], red[3]));

  float s = 0.f;
#pragma unroll
  for (int j = 0; j < 8; ++j) { v[j] = __expf(v[j] - mx); s += v[j]; }
#pragma unroll
  for (int o = 32; o; o >>= 1) s += __shfl_xor(s, o);
  if (lane == 0) red[4 + wid] = s;
  __syncthreads();
  s = red[4] + red[5] + red[6] + red[7];
  const float inv = 1.f / s;

  unsigned short* arow = (unsigned short*)srow;     // in-place bf16, stride 4096
#pragma unroll
  for (int j = 0; j < 8; ++j)
    arow[t + j * 256] = f2bf(v[j] * inv + irow[t + j * 256]);
}

__global__ __launch_bounds__(256) void cvt_bf16(
    const float* __restrict__ in, unsigned short* __restrict__ out, int n)
{
  const int i = (blockIdx.x * 256 + threadIdx.x) * 4;
  if (i >= n) return;
  const float4 f = *(const float4*)(in + i);
  ushort4 o;
  o.x = f2bf(f.x); o.y = f2bf(f.y); o.z = f2bf(f.z); o.w = f2bf(f.w);
  *(ushort4*)(out + i) = o;
}

extern "C" void kernel_launch(void* const* d_in, const int* in_sizes, int n_in,
                              void* d_out, int out_size, void* d_ws, size_t ws_size,
                              hipStream_t stream)
{
  const float* X     = (const float*)d_in[0];
  const float* inten = (const float*)d_in[1];
  const float* Wq = (const float*)d_in[2];
  const float* bq = (const float*)d_in[3];
  const float* Wk = (const float*)d_in[4];
  const float* bk = (const float*)d_in[5];
  const float* Wv = (const float*)d_in[6];
  const float* bv = (const float*)d_in[7];
  const float* Wo = (const float*)d_in[8];
  const float* bo = (const float*)d_in[9];
  float* out = (float*)d_out;

  const int B = 4, S = 2048, D = 1024;
  const int MS = B * S;                 // 8192
  char* ws = (char*)d_ws;
  const size_t MB = 1 << 20;
  unsigned short* Xb  = (unsigned short*)(ws);              // 16 MB
  unsigned short* Wqb = (unsigned short*)(ws + 16 * MB);    //  2 MB
  unsigned short* Wkb = (unsigned short*)(ws + 18 * MB);
  unsigned short* Wvb = (unsigned short*)(ws + 20 * MB);
  unsigned short* Wob = (unsigned short*)(ws + 22 * MB);
  unsigned short* Q   = (unsigned short*)(ws + 24 * MB);    // 16 MB
  unsigned short* Kb  = (unsigned short*)(ws + 40 * MB);    // 16 MB
  unsigned short* Vt  = (unsigned short*)(ws + 56 * MB);    // 16 MB  [B][D][S]
  unsigned short* Oa  = (unsigned short*)(ws + 72 * MB);    // 16 MB
  float*          Sc  = (float*)(ws + 88 * MB);             // 64 MB  [B][S][S]

  // 1) fp32 -> bf16 conversions
  cvt_bf16<<<(MS * D) / 1024, 256, 0, stream>>>(X,  Xb,  MS * D);
  cvt_bf16<<<(D * D) / 1024, 256, 0, stream>>>(Wq, Wqb, D * D);
  cvt_bf16<<<(D * D) / 1024, 256, 0, stream>>>(Wk, Wkb, D * D);
  cvt_bf16<<<(D * D) / 1024, 256, 0, stream>>>(Wv, Wvb, D * D);
  cvt_bf16<<<(D * D) / 1024, 256, 0, stream>>>(Wo, Wob, D * D);

  // 2) Q = Xb @ Wq^T + bq ; K = Xb @ Wk^T + bk     [8192,1024] bf16
  dim3 gproj(MS / 128, D / 128, 1);
  gemm_nt<true, 1><<<gproj, 256, 0, stream>>>(Xb, Wqb, Q,  bq, 1.f, D, D, D, D, 0, 0, 0);
  gemm_nt<true, 1><<<gproj, 256, 0, stream>>>(Xb, Wkb, Kb, bk, 1.f, D, D, D, D, 0, 0, 0);

  // 3) Vt[b] = Wv @ X[b]^T + bv (row bias)         [B][1024][2048] bf16
  dim3 gvt(D / 128, S / 128, B);
  gemm_nt<true, 2><<<gvt, 256, 0, stream>>>(Wvb, Xb, Vt, bv, 1.f, D, D, D, S,
                                            0, (long)S * D, (long)D * S);

  // 4) scores[b] = Q[b] @ K[b]^T / 32              [B][2048][2048] fp32
  dim3 gsc(S / 128, S / 128, B);
  gemm_nt<false, 0><<<gsc, 256, 0, stream>>>(Q, Kb, Sc, nullptr, 0.03125f, D,
                                             D, D, S,
                                             (long)S * D, (long)S * D, (long)S * S);

  // 5) attn = softmax(scores) + intensity, bf16 in-place (row stride 4096)
  softmax_add_bf16<<<B * S, 256, 0, stream>>>(Sc, inten);

  // 6) Oa[b] = attn[b] @ Vt[b]^T                   [B][2048][1024] bf16
  dim3 gav(S / 128, D / 128, B);
  gemm_nt<true, 0><<<gav, 256, 0, stream>>>((unsigned short*)Sc, Vt, Oa, nullptr,
                                            1.f, S, 2 * S, S, D,
                                            (long)S * 2 * S, (long)D * S, (long)S * D);

  // 7) out = Oa @ Wo^T + bo                        [8192,1024] fp32
  gemm_nt<false, 1><<<gproj, 256, 0, stream>>>(Oa, Wob, out, bo, 1.f, D, D, D, D, 0, 0, 0);
}

// Round 2
// 349.829 us; speedup vs baseline: 1.2133x; 1.2133x over previous
//
#include <hip/hip_runtime.h>

typedef __attribute__((ext_vector_type(8))) short bf16x8;
typedef __attribute__((ext_vector_type(4))) float f32x4;

#define LDS_TILE (48 * 1024)   // A 256x64 bf16 (32KB) + B 128x64 bf16 (16KB)
#define NBUF 3
#define LDS_TOTAL (NBUF * LDS_TILE)   // 144 KB

__device__ __forceinline__ unsigned short f2bf(float f) {
  union { float f; unsigned u; } a; a.f = f;
  unsigned u = a.u;
  unsigned r = (u + 0x7FFFu + ((u >> 16) & 1u)) >> 16;  // round-nearest-even
  return (unsigned short)r;
}

__device__ __forceinline__ void stage16(const void* g, void* l) {
  __builtin_amdgcn_global_load_lds((const __attribute__((address_space(1))) unsigned int*)g,
                                   (__attribute__((address_space(3))) unsigned int*)l,
                                   16, 0, 0);
}

// ---------------------------------------------------------------------------
// NT GEMM, C[m,n] = scale * sum_k A[m,k]*B[n,k] (+bias)
// BM=256, BN=128, BK=64, 512 thr = 8 waves (4M x 2N, each 64x64 out).
// 3-buffer LDS pipeline, depth-2 prefetch, vmcnt(6)+s_barrier per K-tile.
// XOR-swizzled LDS (source-side pre-swizzle, linear global_load_lds dest).
// Requires: M%256==0, N%128==0, K%64==0, grid blocks %8==0.
// ---------------------------------------------------------------------------
template<bool OUT_BF16, int BIAS_MODE>
__global__ __launch_bounds__(512) void gemm_nt(
    const unsigned short* __restrict__ A,
    const unsigned short* __restrict__ B,
    void* __restrict__ Cv,
    const float* __restrict__ bias,
    float scale, int K,
    int lda, int ldb, int ldc,
    long batchA, long batchB, long batchC)
{
  extern __shared__ char smem[];

  // ---- bijective XCD-aware block swizzle (nwg % 8 == 0 for all our grids)
  const int gx = gridDim.x, gy = gridDim.y;
  int bid = blockIdx.x + gx * (blockIdx.y + gy * blockIdx.z);
  const int nwg = gx * gy * gridDim.z;
  const int q = nwg >> 3;
  int wg = (bid & 7) * q + (bid >> 3);
  const int tx = wg % gx;
  int rest = wg / gx;
  const int ty = rest % gy;
  const int tz = rest / gy;

  const int tid  = threadIdx.x;
  const int lane = tid & 63;
  const int wid  = tid >> 6;
  const int wm   = wid & 3;      // 0..3 -> rows wm*64
  const int wn   = wid >> 2;     // 0..1 -> cols wn*64

  A += (long)tz * batchA;
  B += (long)tz * batchB;
  const int tileM = tx * 256;
  const int tileN = ty * 128;

  // ---- staging source (pre-swizzled column slot)
  const int srow = tid >> 3;                          // 0..63
  const int scol = (((tid & 7) ^ (srow & 7)) << 3);   // swizzled col (elems)
  const unsigned short* ga[4];
  const unsigned short* gb[2];
#pragma unroll
  for (int j = 0; j < 4; ++j) ga[j] = A + (size_t)(tileM + j * 64 + srow) * lda + scol;
#pragma unroll
  for (int j = 0; j < 2; ++j) gb[j] = B + (size_t)(tileN + j * 64 + srow) * ldb + scol;

  // ---- fragment read offsets (bytes inside a buffer), XOR-swizzled
  const int frow  = lane & 15;
  const int k0slot = (lane >> 4) ^ (lane & 7);        // ksub=1 -> ^4
  const int aoff = (wm * 64 + frow) * 128;            // + m*2048 + slot*16
  const int boff = 32768 + (wn * 64 + frow) * 128;    // + n*2048 + slot*16

  f32x4 acc[4][4];
#pragma unroll
  for (int m = 0; m < 4; ++m)
#pragma unroll
    for (int n = 0; n < 4; ++n) acc[m][n] = (f32x4){0.f, 0.f, 0.f, 0.f};

  const int nt = K >> 6;

#define STAGE(t)                                                         \
  do {                                                                   \
    char* d_ = smem + ((t) % NBUF) * LDS_TILE;                           \
    const int kc_ = (t) << 6;                                            \
    _Pragma("unroll")                                                    \
    for (int j = 0; j < 4; ++j) stage16(ga[j] + kc_, d_ + j * 8192 + tid * 16); \
    _Pragma("unroll")                                                    \
    for (int j = 0; j < 2; ++j) stage16(gb[j] + kc_, d_ + 32768 + j * 8192 + tid * 16); \
  } while (0)

#define COMPUTE(t)                                                       \
  do {                                                                   \
    const char* d_ = smem + ((t) % NBUF) * LDS_TILE;                     \
    bf16x8 af[4][2], bfr[4][2];                                          \
    _Pragma("unroll")                                                    \
    for (int ks = 0; ks < 2; ++ks) {                                     \
      const int so_ = ((k0slot ^ (ks << 2)) << 4);                       \
      _Pragma("unroll")                                                  \
      for (int m = 0; m < 4; ++m)                                        \
        af[m][ks] = *(const bf16x8*)(d_ + aoff + m * 2048 + so_);        \
      _Pragma("unroll")                                                  \
      for (int n = 0; n < 4; ++n)                                        \
        bfr[n][ks] = *(const bf16x8*)(d_ + boff + n * 2048 + so_);       \
    }                                                                    \
    __builtin_amdgcn_s_setprio(1);                                       \
    _Pragma("unroll")                                                    \
    for (int ks = 0; ks < 2; ++ks)                                       \
      _Pragma("unroll")                                                  \
      for (int m = 0; m < 4; ++m)                                        \
        _Pragma("unroll")                                                \
        for (int n = 0; n < 4; ++n)                                      \
          acc[m][n] = __builtin_amdgcn_mfma_f32_16x16x32_bf16(af[m][ks], bfr[n][ks], acc[m][n], 0, 0, 0); \
    __builtin_amdgcn_s_setprio(0);                                       \
  } while (0)

  // prologue: stage tiles 0,1; wait tile0 (6 newest = tile1 may fly)
  STAGE(0);
  STAGE(1);
  asm volatile("s_waitcnt vmcnt(6)" ::: "memory");
  __builtin_amdgcn_s_barrier();

  for (int t = 0; t < nt - 2; ++t) {
    STAGE(t + 2);                 // into buf (t+2)%3 — not read by anyone now
    COMPUTE(t);
    asm volatile("s_waitcnt vmcnt(6)" ::: "memory");   // tile t+1 landed
    __builtin_amdgcn_s_barrier();
  }
  COMPUTE(nt - 2);
  asm volatile("s_waitcnt vmcnt(0)" ::: "memory");     // tile nt-1 landed
  __builtin_amdgcn_s_barrier();
  COMPUTE(nt - 1);

#undef STAGE
#undef COMPUTE

  // ---- epilogue. C/D: col = lane&15, row = (lane>>4)*4 + reg  [m89]
  const int ro = (lane >> 4) << 2;
  const int co = lane & 15;
#pragma unroll
  for (int m = 0; m < 4; ++m) {
#pragma unroll
    for (int n = 0; n < 4; ++n) {
      const int row0 = tileM + wm * 64 + m * 16 + ro;
      const int col  = tileN + wn * 64 + n * 16 + co;
#pragma unroll
      for (int r = 0; r < 4; ++r) {
        float v = acc[m][n][r] * scale;
        const int row = row0 + r;
        if (BIAS_MODE == 1) v += bias[col];
        if (BIAS_MODE == 2) v += bias[row];
        const size_t ci = (size_t)(tz * batchC) + (size_t)row * ldc + col;
        if (OUT_BF16) ((unsigned short*)Cv)[ci] = f2bf(v);
        else          ((float*)Cv)[ci] = v;
      }
    }
  }
}

// ---------------------------------------------------------------------------
// Row softmax over 2048 fp32 scores + intensity add, bf16 written IN-PLACE
// (attn row i at bf16-elem offset i*4096). One 256-thr block per row.
// ---------------------------------------------------------------------------
__global__ __launch_bounds__(256) void softmax_add_bf16(
    float* __restrict__ scores, const float* __restrict__ inten)
{
  const int row = blockIdx.x;
  float* srow = scores + (size_t)row * 2048;
  const float* irow = inten + (size_t)row * 2048;
  const int t = threadIdx.x;
  const int lane = t & 63, wid = t >> 6;

  float v[8];
  float mx = -3.4e38f;
#pragma unroll
  for (int j = 0; j < 8; ++j) { v[j] = srow[t + j * 256]; mx = fmaxf(mx, v[j]); }

  __shared__ float red[8];
#pragma unroll
  for (int o = 32; o; o >>= 1) mx = fmaxf(mx, __shfl_xor(mx, o));
  if (lane == 0) red[wid] = mx;
  __syncthreads();
  mx = fmaxf(fmaxf(red[0], red[1]), fmaxf(red[2], red[3]));

  float s = 0.f;
#pragma unroll
  for (int j = 0; j < 8; ++j) { v[j] = __expf(v[j] - mx); s += v[j]; }
#pragma unroll
  for (int o = 32; o; o >>= 1) s += __shfl_xor(s, o);
  if (lane == 0) red[4 + wid] = s;
  __syncthreads();
  s = red[4] + red[5] + red[6] + red[7];
  const float inv = 1.f / s;

  unsigned short* arow = (unsigned short*)srow;   // in-place bf16, stride 4096
#pragma unroll
  for (int j = 0; j < 8; ++j)
    arow[t + j * 256] = f2bf(v[j] * inv + irow[t + j * 256]);
}

__global__ __launch_bounds__(256) void cvt_bf16(
    const float* __restrict__ in, unsigned short* __restrict__ out, int n)
{
  const int i = (blockIdx.x * 256 + threadIdx.x) * 4;
  if (i >= n) return;
  const float4 f = *(const float4*)(in + i);
  ushort4 o;
  o.x = f2bf(f.x); o.y = f2bf(f.y); o.z = f2bf(f.z); o.w = f2bf(f.w);
  *(ushort4*)(out + i) = o;
}

extern "C" void kernel_launch(void* const* d_in, const int* in_sizes, int n_in,
                              void* d_out, int out_size, void* d_ws, size_t ws_size,
                              hipStream_t stream)
{
  const float* X     = (const float*)d_in[0];
  const float* inten = (const float*)d_in[1];
  const float* Wq = (const float*)d_in[2];
  const float* bq = (const float*)d_in[3];
  const float* Wk = (const float*)d_in[4];
  const float* bk = (const float*)d_in[5];
  const float* Wv = (const float*)d_in[6];
  const float* bv = (const float*)d_in[7];
  const float* Wo = (const float*)d_in[8];
  const float* bo = (const float*)d_in[9];
  float* out = (float*)d_out;

  const int B = 4, S = 2048, D = 1024;
  const int MS = B * S;                 // 8192
  char* ws = (char*)d_ws;
  const size_t MB = 1 << 20;
  unsigned short* Xb  = (unsigned short*)(ws);              // 16 MB
  unsigned short* Wqb = (unsigned short*)(ws + 16 * MB);    //  2 MB
  unsigned short* Wkb = (unsigned short*)(ws + 18 * MB);
  unsigned short* Wvb = (unsigned short*)(ws + 20 * MB);
  unsigned short* Wob = (unsigned short*)(ws + 22 * MB);
  unsigned short* Q   = (unsigned short*)(ws + 24 * MB);    // 16 MB
  unsigned short* Kb  = (unsigned short*)(ws + 40 * MB);    // 16 MB
  unsigned short* Vt  = (unsigned short*)(ws + 56 * MB);    // 16 MB  [B][D][S]
  unsigned short* Oa  = (unsigned short*)(ws + 72 * MB);    // 16 MB
  float*          Sc  = (float*)(ws + 88 * MB);             // 64 MB  [B][S][S]

  // allow 144 KB dynamic LDS on every instantiation we use (idempotent)
  hipFuncSetAttribute((const void*)gemm_nt<true, 1>,  hipFuncAttributeMaxDynamicSharedMemorySize, LDS_TOTAL);
  hipFuncSetAttribute((const void*)gemm_nt<true, 2>,  hipFuncAttributeMaxDynamicSharedMemorySize, LDS_TOTAL);
  hipFuncSetAttribute((const void*)gemm_nt<false, 0>, hipFuncAttributeMaxDynamicSharedMemorySize, LDS_TOTAL);
  hipFuncSetAttribute((const void*)gemm_nt<true, 0>,  hipFuncAttributeMaxDynamicSharedMemorySize, LDS_TOTAL);
  hipFuncSetAttribute((const void*)gemm_nt<false, 1>, hipFuncAttributeMaxDynamicSharedMemorySize, LDS_TOTAL);

  // 1) fp32 -> bf16 conversions
  cvt_bf16<<<(MS * D) / 1024, 256, 0, stream>>>(X,  Xb,  MS * D);
  cvt_bf16<<<(D * D) / 1024, 256, 0, stream>>>(Wq, Wqb, D * D);
  cvt_bf16<<<(D * D) / 1024, 256, 0, stream>>>(Wk, Wkb, D * D);
  cvt_bf16<<<(D * D) / 1024, 256, 0, stream>>>(Wv, Wvb, D * D);
  cvt_bf16<<<(D * D) / 1024, 256, 0, stream>>>(Wo, Wob, D * D);

  // 2) Q = Xb @ Wq^T + bq ; K = Xb @ Wk^T + bk     [8192,1024] bf16
  dim3 gproj(MS / 256, D / 128, 1);   // 32x8 = 256 blocks
  gemm_nt<true, 1><<<gproj, 512, LDS_TOTAL, stream>>>(Xb, Wqb, Q,  bq, 1.f, D, D, D, D, 0, 0, 0);
  gemm_nt<true, 1><<<gproj, 512, LDS_TOTAL, stream>>>(Xb, Wkb, Kb, bk, 1.f, D, D, D, D, 0, 0, 0);

  // 3) Vt[b] = Wv @ X[b]^T + bv (row bias)         [B][1024][2048] bf16
  dim3 gvt(D / 256, S / 128, B);      // 4x16x4 = 256 blocks
  gemm_nt<true, 2><<<gvt, 512, LDS_TOTAL, stream>>>(Wvb, Xb, Vt, bv, 1.f, D, D, D, S,
                                                    0, (long)S * D, (long)D * S);

  // 4) scores[b] = Q[b] @ K[b]^T / 32              [B][2048][2048] fp32
  dim3 gsc(S / 256, S / 128, B);      // 8x16x4 = 512 blocks
  gemm_nt<false, 0><<<gsc, 512, LDS_TOTAL, stream>>>(Q, Kb, Sc, nullptr, 0.03125f, D,
                                                     D, D, S,
                                                     (long)S * D, (long)S * D, (long)S * S);

  // 5) attn = softmax(scores) + intensity, bf16 in-place (row stride 4096)
  softmax_add_bf16<<<B * S, 256, 0, stream>>>(Sc, inten);

  // 6) Oa[b] = attn[b] @ Vt[b]^T                   [B][2048][1024] bf16
  dim3 gav(S / 256, D / 128, B);      // 8x8x4 = 256 blocks
  gemm_nt<true, 0><<<gav, 512, LDS_TOTAL, stream>>>((unsigned short*)Sc, Vt, Oa, nullptr,
                                                    1.f, S, 2 * S, S, D,
                                                    (long)S * 2 * S, (long)D * S, (long)S * D);

  // 7) out = Oa @ Wo^T + bo                        [8192,1024] fp32
  gemm_nt<false, 1><<<gproj, 512, LDS_TOTAL, stream>>>(Oa, Wob, out, bo, 1.f, D, D, D, D, 0, 0, 0);
}